// Round 5
// baseline (39.172 us; speedup 1.0000x reference)
//
#include <hip/hip_runtime.h>

#define NB 4
#define NC 128
#define NH 128
#define NW 128
#define EPSV 0.2f
#define TH 2

typedef float v4f __attribute__((ext_vector_type(4)));

// ---------------- Kernel 1: channel mean -----------------------------------
// 512 blocks x 256 thr. Block covers 32 float4 positions; threads are
// (pos 0..31) x (cgroup 0..7), each summing 16 channels; LDS reduce 8-way.
__global__ __launch_bounds__(256) void mean_kernel(const float* __restrict__ x,
                                                   float* __restrict__ mean) {
    const int tid = threadIdx.x;
    const int pos = tid & 31;
    const int cg  = tid >> 5;
    const int gpos = blockIdx.x * 32 + pos;
    const int b    = gpos >> 12;
    const int pos4 = gpos & 4095;

    const float4* x4 = (const float4*)x;
    float4 acc = make_float4(0.f, 0.f, 0.f, 0.f);
    const int cbase = (b * NC + cg * 16) * (NH * NW / 4) + pos4;
    #pragma unroll
    for (int cc = 0; cc < 16; ++cc) {
        float4 v = x4[cbase + cc * (NH * NW / 4)];
        acc.x += v.x; acc.y += v.y; acc.z += v.z; acc.w += v.w;
    }

    __shared__ float4 red[256];
    red[tid] = acc;
    __syncthreads();
    if (tid < 32) {
        float4 s = red[tid];
        #pragma unroll
        for (int g = 1; g < 8; ++g) {
            float4 v = red[tid + 32 * g];
            s.x += v.x; s.y += v.y; s.z += v.z; s.w += v.w;
        }
        const float inv = 1.0f / NC;
        s.x *= inv; s.y *= inv; s.z *= inv; s.w *= inv;
        ((float4*)mean)[blockIdx.x * 32 + tid] = s;
    }
}

// ---------------- Kernel 2: weights + reassembly ---------------------------
// 256 blocks (b, h-pair, XCD-swizzled) x 1024 threads.
// Phase B: 256 threads compute 9-tap softmax weights from global mean -> LDS.
// Phase C: thread = (wp 0..63, cg 0..15); 8 channels each; x reads are
//          LLC-hits (K1 just streamed x); stores are 16B nontemporal float4.
__global__ __launch_bounds__(1024) void carafe_kernel(const float* __restrict__ x,
                                                      const float* __restrict__ mean,
                                                      float* __restrict__ out) {
    const int chunk = gridDim.x >> 3;            // 32
    const int bid = blockIdx.x;
    const int swz = (bid & 7) * chunk + (bid >> 3);
    const int b  = swz >> 6;
    const int h0 = (swz & 63) * TH;

    __shared__ float wgt[TH][9][NW];             // 9 KB

    const int tid = threadIdx.x;
    const float* mb = mean + (size_t)b * NH * NW;

    if (tid < 256) {                             // phase B
        const int r = tid >> 7;
        const int w = tid & 127;
        const int h = h0 + r;
        const float mc = mb[h * NW + w];
        float v[9];
        float vmax = -1e30f;
        #pragma unroll
        for (int ky = -1; ky <= 1; ++ky) {
            #pragma unroll
            for (int kx = -1; kx <= 1; ++kx) {
                const int hh = h + ky, ww = w + kx;
                const float mp = (hh >= 0 && hh < NH && ww >= 0 && ww < NW)
                                     ? mb[hh * NW + ww] : 0.0f;
                const float g = mp - mc;
                const float val = 1.0f / (g * g + EPSV);
                v[(ky + 1) * 3 + (kx + 1)] = val;
                vmax = fmaxf(vmax, val);
            }
        }
        float sum = 0.f;
        #pragma unroll
        for (int k = 0; k < 9; ++k) { v[k] = __expf(v[k] - vmax); sum += v[k]; }
        const float rs = 1.0f / sum;
        #pragma unroll
        for (int k = 0; k < 9; ++k) wgt[r][k][w] = v[k] * rs;
    }
    __syncthreads();

    // phase C
    const int wp = tid & 63;                     // source cols 2wp, 2wp+1
    const int cg = tid >> 6;                     // 0..15 -> 8 channels each
    const int wa = 2 * wp;

    float wA0[9], wB0[9], wA1[9], wB1[9];
    #pragma unroll
    for (int k = 0; k < 9; ++k) {
        wA0[k] = wgt[0][k][wa];  wB0[k] = wgt[0][k][wa + 1];
        wA1[k] = wgt[1][k][wa];  wB1[k] = wgt[1][k][wa + 1];
    }

    const bool rv0 = (h0 > 0), rv3 = (h0 + 2 < NH);
    const bool tv0 = (wp > 0), tv3 = (wp < 63);

    #pragma unroll 2
    for (int i = 0; i < 8; ++i) {
        const int c = cg * 8 + i;
        const float* xc = x + ((size_t)(b * NC + c)) * (NH * NW);

        float a[4][4];                           // rows h0-1..h0+2, taps wa-1..wa+2
        #pragma unroll
        for (int rr = 0; rr < 4; ++rr) {
            const int hh = h0 - 1 + rr;
            const bool rv = (rr == 0) ? rv0 : ((rr == 3) ? rv3 : true);
            const float* row = xc + hh * NW + wa;
            a[rr][0] = (rv && tv0) ? row[-1] : 0.f;
            a[rr][1] = rv ? row[0] : 0.f;
            a[rr][2] = rv ? row[1] : 0.f;
            a[rr][3] = (rv && tv3) ? row[2] : 0.f;
        }

        float v0a = 0.f, v0b = 0.f, v1a = 0.f, v1b = 0.f;
        #pragma unroll
        for (int ky = 0; ky < 3; ++ky) {
            #pragma unroll
            for (int kx = 0; kx < 3; ++kx) {
                const int k = ky * 3 + kx;
                v0a += wA0[k] * a[ky][kx];
                v0b += wB0[k] * a[ky][kx + 1];
                v1a += wA1[k] * a[ky + 1][kx];
                v1b += wB1[k] * a[ky + 1][kx + 1];
            }
        }

        float* o = out + ((size_t)(b * NC + c) * (NH * 2) + 2 * h0) * (NW * 2) + 4 * wp;
        const v4f p0 = {v0a, v0a, v0b, v0b};
        const v4f p1 = {v1a, v1a, v1b, v1b};
        __builtin_nontemporal_store(p0, (v4f*)(o));
        __builtin_nontemporal_store(p0, (v4f*)(o + (NW * 2)));
        __builtin_nontemporal_store(p1, (v4f*)(o + 2 * (NW * 2)));
        __builtin_nontemporal_store(p1, (v4f*)(o + 3 * (NW * 2)));
    }
}

extern "C" void kernel_launch(void* const* d_in, const int* in_sizes, int n_in,
                              void* d_out, int out_size, void* d_ws, size_t ws_size,
                              hipStream_t stream) {
    const float* x = (const float*)d_in[0];
    float* out = (float*)d_out;
    float* mean = (float*)d_ws;   // 256 KB

    mean_kernel<<<dim3(512), dim3(256), 0, stream>>>(x, mean);
    carafe_kernel<<<dim3(NB * NH / TH), dim3(1024), 0, stream>>>(x, mean, out);
}

// Round 6
// 37.861 us; speedup vs baseline: 1.0346x; 1.0346x over previous
//
#include <hip/hip_runtime.h>

#define NB 4
#define NC 128
#define NH 128
#define NW 128
#define EPSV 0.2f
#define TH 2

typedef float v4f __attribute__((ext_vector_type(4)));

// One fused kernel. Grid: 256 blocks = (b, h-pair), XCD-swizzled. 512 threads.
// Phase A: channel-mean rows h0-1..h0+2 -> LDS.
// Phase B: 9-tap softmax weights for rows h0,h0+1 -> LDS.
// Phase C: reassembly; thread = (w-pair, channel-group of 16); all output
//          stores are plain 16B float4 (A/B vs R4: NT removed).
__global__ __launch_bounds__(512) void fused_carafe(const float* __restrict__ x,
                                                    float* __restrict__ out) {
    const int chunk = gridDim.x >> 3;            // 32
    const int bid = blockIdx.x;
    const int swz = (bid & 7) * chunk + (bid >> 3);
    const int b  = swz >> 6;
    const int h0 = (swz & 63) * TH;

    __shared__ float mrow[4][NW];                // mean rows h0-1..h0+2
    __shared__ float wgt[TH][9][NW];             // softmax weights

    const int tid = threadIdx.x;

    // ---------------- Phase A: channel means ----------------
    {
        const int r = tid >> 7;                  // 0..3
        const int w = tid & 127;
        const int hh = h0 - 1 + r;
        float s = 0.f;
        if (hh >= 0 && hh < NH) {
            const float* px = x + ((size_t)b * NC * NH + hh) * NW + w;
            #pragma unroll 16
            for (int c = 0; c < NC; ++c)
                s += px[(size_t)c * NH * NW];
        }
        mrow[r][w] = s * (1.0f / NC);            // out-of-range row -> 0 (zero pad)
    }
    __syncthreads();

    // ---------------- Phase B: softmax weights ----------------
    if (tid < 256) {
        const int r = tid >> 7;                  // 0..1 -> source row h0+r
        const int w = tid & 127;
        const float mc = mrow[r + 1][w];
        float v[9];
        float vmax = -1e30f;
        #pragma unroll
        for (int ky = 0; ky < 3; ++ky) {
            #pragma unroll
            for (int kx = -1; kx <= 1; ++kx) {
                const int ww = w + kx;
                const float mp = (ww >= 0 && ww < NW) ? mrow[r + ky][ww] : 0.f;
                const float g = mp - mc;
                const float val = 1.0f / (g * g + EPSV);
                v[ky * 3 + kx + 1] = val;
                vmax = fmaxf(vmax, val);
            }
        }
        float sum = 0.f;
        #pragma unroll
        for (int k = 0; k < 9; ++k) { v[k] = __expf(v[k] - vmax); sum += v[k]; }
        const float rs = 1.0f / sum;
        #pragma unroll
        for (int k = 0; k < 9; ++k) wgt[r][k][w] = v[k] * rs;
    }
    __syncthreads();

    // ---------------- Phase C: reassembly ----------------
    const int wp = tid & 63;                     // source cols 2wp, 2wp+1
    const int cg = tid >> 6;                     // 0..7 -> 16 channels each
    const int wa = 2 * wp;

    float wA0[9], wB0[9], wA1[9], wB1[9];
    #pragma unroll
    for (int k = 0; k < 9; ++k) {
        wA0[k] = wgt[0][k][wa];  wB0[k] = wgt[0][k][wa + 1];
        wA1[k] = wgt[1][k][wa];  wB1[k] = wgt[1][k][wa + 1];
    }

    const bool rv0 = (h0 > 0), rv3 = (h0 + 2 < NH);
    const bool tv0 = (wp > 0), tv3 = (wp < 63);

    #pragma unroll 2
    for (int i = 0; i < 16; ++i) {
        const int c = cg * 16 + i;
        const float* xc = x + ((size_t)(b * NC + c)) * (NH * NW);

        float a[4][4];                           // rows h0-1..h0+2, taps wa-1..wa+2
        #pragma unroll
        for (int rr = 0; rr < 4; ++rr) {
            const int hh = h0 - 1 + rr;
            const bool rv = (rr == 0) ? rv0 : ((rr == 3) ? rv3 : true);
            const float* row = xc + hh * NW + wa;
            a[rr][0] = (rv && tv0) ? row[-1] : 0.f;
            a[rr][1] = rv ? row[0] : 0.f;
            a[rr][2] = rv ? row[1] : 0.f;
            a[rr][3] = (rv && tv3) ? row[2] : 0.f;
        }

        float v0a = 0.f, v0b = 0.f, v1a = 0.f, v1b = 0.f;
        #pragma unroll
        for (int ky = 0; ky < 3; ++ky) {
            #pragma unroll
            for (int kx = 0; kx < 3; ++kx) {
                const int k = ky * 3 + kx;
                v0a += wA0[k] * a[ky][kx];
                v0b += wB0[k] * a[ky][kx + 1];
                v1a += wA1[k] * a[ky + 1][kx];
                v1b += wB1[k] * a[ky + 1][kx + 1];
            }
        }

        float* o = out + ((size_t)(b * NC + c) * (NH * 2) + 2 * h0) * (NW * 2) + 4 * wp;
        const v4f p0 = {v0a, v0a, v0b, v0b};
        const v4f p1 = {v1a, v1a, v1b, v1b};
        *(v4f*)(o)                = p0;
        *(v4f*)(o + (NW * 2))     = p0;
        *(v4f*)(o + 2 * (NW * 2)) = p1;
        *(v4f*)(o + 3 * (NW * 2)) = p1;
    }
}

extern "C" void kernel_launch(void* const* d_in, const int* in_sizes, int n_in,
                              void* d_out, int out_size, void* d_ws, size_t ws_size,
                              hipStream_t stream) {
    const float* x = (const float*)d_in[0];
    float* out = (float*)d_out;
    fused_carafe<<<dim3(NB * NH / TH), dim3(512), 0, stream>>>(x, out);
}